// Round 3
// baseline (243.154 us; speedup 1.0000x reference)
//
#include <hip/hip_runtime.h>

#define NN 50000
#define FF 128
constexpr int NBF2 = NN * 256;   // bf16 elements of x0b, layout [n][b][f]
constexpr int CAP  = 64;         // edge-bucket capacity per node (Poisson(10): safe)
constexpr int CSTR = 16;         // cursor stride (ints): 1 counter per 64B line

typedef __attribute__((ext_vector_type(4))) short short4v;  // 4 bf16 = 1 dwordx2
typedef __attribute__((ext_vector_type(8))) short short8;   // 8 bf16 = 4 VGPRs
typedef __attribute__((ext_vector_type(4))) float floatx4;  // MFMA C/D frag

__device__ __forceinline__ unsigned short f2bf(float x) {
    unsigned int u = __float_as_uint(x);
    unsigned int r = (u + 0x7fff + ((u >> 16) & 1)) >> 16;  // RNE, no NaNs here
    return (unsigned short)r;
}
__device__ __forceinline__ float bf2f(short x) {
    return __uint_as_float(((unsigned int)(unsigned short)x) << 16);
}

// ---- Bucket-fill edges + convert x0/w0/w1 to bf16 (one kernel) ----
__global__ __launch_bounds__(256)
void convert_fill(const int* __restrict__ dst, const int* __restrict__ src, int E,
                  const float* __restrict__ x0,
                  const float* __restrict__ w0, const float* __restrict__ w1,
                  int* __restrict__ cursor, unsigned short* __restrict__ esrc,
                  unsigned short* __restrict__ x0b,
                  unsigned short* __restrict__ w0b, unsigned short* __restrict__ w1b) {
    int i = blockIdx.x * 256 + threadIdx.x;
    if (i < E) {
        int d = dst[i];
        int pos = atomicAdd(&cursor[d * CSTR], 1);
        if (pos < CAP) esrc[d * CAP + pos] = (unsigned short)src[i];
    }
    // x0 [b][n][f] fp32 -> x0b [n][b][f] bf16, float4 -> 4xbf16 per step
    int stride = gridDim.x * 256;
    for (int p = i; p < NBF2 / 4; p += stride) {
        int v0 = p * 4;
        int n = v0 >> 8;
        int b = (v0 >> 7) & 1;
        int f = v0 & 127;
        const float4 in = *(const float4*)&x0[(b * NN + n) * FF + f];
        short4v o = { (short)f2bf(in.x), (short)f2bf(in.y), (short)f2bf(in.z), (short)f2bf(in.w) };
        *(short4v*)&x0b[v0] = o;
    }
    if (i < 128 * 256) w0b[i] = f2bf(w0[i]);
    if (i < 128 * 128) w1b[i] = f2bf(w1[i]);
}

// ---------------- Fused reduce + MFMA MLP ----------------
constexpr int NPB = 8;           // nodes per block (2 per wave)
constexpr int XCP = 256 + 8;     // xc row pitch (bf16); row stride 528B (16B-aligned)
constexpr int HSP = 128 + 8;     // hs row pitch (bf16); row stride 272B (16B-aligned)

__global__ __launch_bounds__(256, 8)
void fused_gcn(const unsigned short* __restrict__ x0b,
               const float* __restrict__ x0,
               const int* __restrict__ deg,      // = cursor (stride CSTR) after fill
               const unsigned short* __restrict__ esrc,
               const unsigned short* __restrict__ w0b,
               const float* __restrict__ b0,
               const unsigned short* __restrict__ w1b,
               const float* __restrict__ b1,
               float* __restrict__ out) {
    __shared__ unsigned short xc[16 * XCP];   // 8.4 KB
    __shared__ unsigned short hs[16 * HSP];   // 4.35 KB  -> 12.8 KB total, 8 blocks/CU ok

    int t = threadIdx.x;
    int q = t >> 6;        // wave id (0..3)
    int l = t & 63;        // lane
    int n0 = blockIdx.x * NPB;
    int nA = n0 + q * 2;   // wave q owns nodes nA, nA+1
    int nB = nA + 1;

    int l4 = l * 4;             // bf16 value index in [b][f] row-pair
    int bb = l >> 5;            // batch
    int ff = (l & 31) * 4;      // feature base
    const float NEG_INF = __int_as_float(0xFF800000);

    // Bucket loads: lane l holds edge l's src id (garbage beyond deg -> guarded/clamped)
    int vA = esrc[nA * CAP + l];
    int vB = esrc[nB * CAP + l];
    int dA = min(__builtin_amdgcn_readfirstlane(deg[nA * CSTR]), CAP);
    int dB = min(__builtin_amdgcn_readfirstlane(deg[nB * CSTR]), CAP);

    float sA0=0,sA1=0,sA2=0,sA3=0, sB0=0,sB1=0,sB2=0,sB3=0;
    float mA0=NEG_INF,mA1=NEG_INF,mA2=NEG_INF,mA3=NEG_INF;
    float mB0=NEG_INF,mB1=NEG_INF,mB2=NEG_INF,mB3=NEG_INF;

#define ACCV(r, S0,S1,S2,S3, M0,M1,M2,M3) { \
    float v0=bf2f(r[0]), v1=bf2f(r[1]), v2=bf2f(r[2]), v3=bf2f(r[3]); \
    S0+=v0; S1+=v1; S2+=v2; S3+=v3; \
    M0=fmaxf(M0,v0); M1=fmaxf(M1,v1); M2=fmaxf(M2,v2); M3=fmaxf(M3,v3); }

    // Gather loop: broadcast src ids via v_readlane (no LDS), 8 loads in flight.
#define GLOOP(vv, dd, S0,S1,S2,S3, M0,M1,M2,M3) \
    for (int k = 0; k < dd; k += 8) { \
        int u0 = __builtin_amdgcn_readlane(vv, k + 0); u0 = (u0 < NN) ? u0 : 0; \
        int u1 = __builtin_amdgcn_readlane(vv, k + 1); u1 = (u1 < NN) ? u1 : 0; \
        int u2 = __builtin_amdgcn_readlane(vv, k + 2); u2 = (u2 < NN) ? u2 : 0; \
        int u3 = __builtin_amdgcn_readlane(vv, k + 3); u3 = (u3 < NN) ? u3 : 0; \
        int u4 = __builtin_amdgcn_readlane(vv, k + 4); u4 = (u4 < NN) ? u4 : 0; \
        int u5 = __builtin_amdgcn_readlane(vv, k + 5); u5 = (u5 < NN) ? u5 : 0; \
        int u6 = __builtin_amdgcn_readlane(vv, k + 6); u6 = (u6 < NN) ? u6 : 0; \
        int u7 = __builtin_amdgcn_readlane(vv, k + 7); u7 = (u7 < NN) ? u7 : 0; \
        short4v r0 = *(const short4v*)&x0b[(u0 << 8) + l4]; \
        short4v r1 = *(const short4v*)&x0b[(u1 << 8) + l4]; \
        short4v r2 = *(const short4v*)&x0b[(u2 << 8) + l4]; \
        short4v r3 = *(const short4v*)&x0b[(u3 << 8) + l4]; \
        short4v r4 = *(const short4v*)&x0b[(u4 << 8) + l4]; \
        short4v r5 = *(const short4v*)&x0b[(u5 << 8) + l4]; \
        short4v r6 = *(const short4v*)&x0b[(u6 << 8) + l4]; \
        short4v r7 = *(const short4v*)&x0b[(u7 << 8) + l4]; \
        ACCV(r0, S0,S1,S2,S3, M0,M1,M2,M3) \
        if (k + 1 < dd) ACCV(r1, S0,S1,S2,S3, M0,M1,M2,M3) \
        if (k + 2 < dd) ACCV(r2, S0,S1,S2,S3, M0,M1,M2,M3) \
        if (k + 3 < dd) ACCV(r3, S0,S1,S2,S3, M0,M1,M2,M3) \
        if (k + 4 < dd) ACCV(r4, S0,S1,S2,S3, M0,M1,M2,M3) \
        if (k + 5 < dd) ACCV(r5, S0,S1,S2,S3, M0,M1,M2,M3) \
        if (k + 6 < dd) ACCV(r6, S0,S1,S2,S3, M0,M1,M2,M3) \
        if (k + 7 < dd) ACCV(r7, S0,S1,S2,S3, M0,M1,M2,M3) \
    }

    GLOOP(vA, dA, sA0,sA1,sA2,sA3, mA0,mA1,mA2,mA3)
    GLOOP(vB, dB, sB0,sB1,sB2,sB3, mB0,mB1,mB2,mB3)
#undef GLOOP
#undef ACCV

#define FINAL_N(g, nn, dgx, S0,S1,S2,S3, M0,M1,M2,M3) { \
    float me0,me1,me2,me3,a0,a1,a2,a3; \
    if (dgx > 0) { \
        float inv = 1.0f / (float)dgx; \
        me0=S0*inv; me1=S1*inv; me2=S2*inv; me3=S3*inv; \
        a0=M0; a1=M1; a2=M2; a3=M3; \
    } else { \
        short4v rr = *(const short4v*)&x0b[((nn) << 8) + l4]; \
        me0=a0=bf2f(rr[0]); me1=a1=bf2f(rr[1]); me2=a2=bf2f(rr[2]); me3=a3=bf2f(rr[3]); \
    } \
    int row = (q * 2 + g) * 2 + bb; \
    short4v mv = { (short)f2bf(me0),(short)f2bf(me1),(short)f2bf(me2),(short)f2bf(me3) }; \
    short4v av = { (short)f2bf(a0),(short)f2bf(a1),(short)f2bf(a2),(short)f2bf(a3) }; \
    *(short4v*)&xc[row * XCP + ff]       = mv; \
    *(short4v*)&xc[row * XCP + 128 + ff] = av; \
}
    FINAL_N(0, nA, dA, sA0,sA1,sA2,sA3, mA0,mA1,mA2,mA3)
    FINAL_N(1, nB, dB, sB0,sB1,sB2,sB3, mB0,mB1,mB2,mB3)
#undef FINAL_N
    __syncthreads();

    // ---- MFMA MLP: 16 rows x 128 cols; wave q owns 32 cols (2 tiles of 16) ----
    int m    = l & 15;
    int quad = l >> 4;
    int colbase = q * 32;

    floatx4 acc[2];
#pragma unroll
    for (int ct = 0; ct < 2; ++ct) acc[ct] = (floatx4){0.f, 0.f, 0.f, 0.f};
#pragma unroll
    for (int ks = 0; ks < 8; ++ks) {
        short8 a = *(const short8*)&xc[m * XCP + ks * 32 + quad * 8];
#pragma unroll
        for (int ct = 0; ct < 2; ++ct) {
            short8 bfr = *(const short8*)&w0b[(colbase + ct * 16 + m) * 256 + ks * 32 + quad * 8];
            acc[ct] = __builtin_amdgcn_mfma_f32_16x16x32_bf16(a, bfr, acc[ct], 0, 0, 0);
        }
    }
#pragma unroll
    for (int ct = 0; ct < 2; ++ct) {
        int col = colbase + ct * 16 + m;
        float bias = b0[col];
#pragma unroll
        for (int r = 0; r < 4; ++r) {
            int row = quad * 4 + r;
            hs[row * HSP + col] = f2bf(fmaxf(acc[ct][r] + bias, 0.0f));
        }
    }
    __syncthreads();

    floatx4 acc2[2];
#pragma unroll
    for (int ct = 0; ct < 2; ++ct) acc2[ct] = (floatx4){0.f, 0.f, 0.f, 0.f};
#pragma unroll
    for (int ks = 0; ks < 4; ++ks) {
        short8 a = *(const short8*)&hs[m * HSP + ks * 32 + quad * 8];
#pragma unroll
        for (int ct = 0; ct < 2; ++ct) {
            short8 bfr = *(const short8*)&w1b[(colbase + ct * 16 + m) * 128 + ks * 32 + quad * 8];
            acc2[ct] = __builtin_amdgcn_mfma_f32_16x16x32_bf16(a, bfr, acc2[ct], 0, 0, 0);
        }
    }
#pragma unroll
    for (int ct = 0; ct < 2; ++ct) {
        int col = colbase + ct * 16 + m;
        float bias = b1[col];
#pragma unroll
        for (int r = 0; r < 4; ++r) {
            int row = quad * 4 + r;
            int n  = n0 + (row >> 1);
            int b2 = row & 1;
            int oi = (b2 * NN + n) * FF + col;
            out[oi] = x0[oi] + bias + acc2[ct][r];
        }
    }
}

extern "C" void kernel_launch(void* const* d_in, const int* in_sizes, int n_in,
                              void* d_out, int out_size, void* d_ws, size_t ws_size,
                              hipStream_t stream) {
    const float* x0  = (const float*)d_in[0];
    const int*   dst = (const int*)d_in[1];
    const int*   src = (const int*)d_in[2];
    const float* w0  = (const float*)d_in[3];
    const float* b0  = (const float*)d_in[4];
    const float* w1  = (const float*)d_in[5];
    const float* b1  = (const float*)d_in[6];
    float* out = (float*)d_out;
    int E = in_sizes[1];

    // ws layout: cursor (NN*CSTR ints, padded) | esrc (NN*CAP ushort) | x0b | w0b | w1b
    int* cursor = (int*)d_ws;
    unsigned short* esrc = (unsigned short*)(cursor + (size_t)NN * CSTR);
    unsigned short* x0b  = esrc + (size_t)NN * CAP;
    unsigned short* w0b  = x0b + NBF2;
    unsigned short* w1b  = w0b + 128 * 256;

    int eb = (E + 255) / 256;

    hipMemsetAsync(cursor, 0, (size_t)NN * CSTR * sizeof(int), stream);
    convert_fill<<<eb, 256, 0, stream>>>(dst, src, E, x0, w0, w1, cursor, esrc, x0b, w0b, w1b);
    fused_gcn<<<NN / NPB, 256, 0, stream>>>(x0b, x0, cursor, esrc, w0b, b0, w1b, b1, out);
}

// Round 5
// 236.405 us; speedup vs baseline: 1.0285x; 1.0285x over previous
//
#include <hip/hip_runtime.h>

#define NN 50000
#define FF 128
constexpr int NBF2 = NN * 256;   // bf16 elements of x0b, layout [n][b][f]
constexpr int CAP  = 64;         // edge-bucket capacity per node (Poisson(10): safe)
constexpr int CSTR = 16;         // cursor stride (ints): 1 counter per 64B line

typedef __attribute__((ext_vector_type(4))) short short4v;  // 4 bf16
typedef __attribute__((ext_vector_type(8))) short short8;   // 8 bf16 = 4 VGPRs
typedef __attribute__((ext_vector_type(4))) float floatx4;  // MFMA C/D frag / NT loads

__device__ __forceinline__ unsigned short f2bf(float x) {
    unsigned int u = __float_as_uint(x);
    unsigned int r = (u + 0x7fff + ((u >> 16) & 1)) >> 16;  // RNE, no NaNs here
    return (unsigned short)r;
}
__device__ __forceinline__ float bf2f(short x) {
    return __uint_as_float(((unsigned int)(unsigned short)x) << 16);
}

// ---- Bucket-fill edges + convert x0/w0/w1 to bf16 (one kernel) ----
__global__ __launch_bounds__(256)
void convert_fill(const int* __restrict__ dst, const int* __restrict__ src, int E,
                  const float* __restrict__ x0,
                  const float* __restrict__ w0, const float* __restrict__ w1,
                  int* __restrict__ cursor, unsigned short* __restrict__ esrc,
                  unsigned short* __restrict__ x0b,
                  unsigned short* __restrict__ w0b, unsigned short* __restrict__ w1b) {
    int i = blockIdx.x * 256 + threadIdx.x;
    if (i < E) {
        int d = dst[i];
        int pos = atomicAdd(&cursor[d * CSTR], 1);
        if (pos < CAP) esrc[d * CAP + pos] = (unsigned short)src[i];
    }
    // x0 [b][n][f] fp32 -> x0b [n][b][f] bf16; nontemporal read (keep L3 for x0b)
    int stride = gridDim.x * 256;
    for (int p = i; p < NBF2 / 4; p += stride) {
        int v0 = p * 4;
        int n = v0 >> 8;
        int b = (v0 >> 7) & 1;
        int f = v0 & 127;
        floatx4 in = __builtin_nontemporal_load((const floatx4*)&x0[(b * NN + n) * FF + f]);
        short4v o = { (short)f2bf(in.x), (short)f2bf(in.y), (short)f2bf(in.z), (short)f2bf(in.w) };
        *(short4v*)&x0b[v0] = o;
    }
    if (i < 128 * 256) w0b[i] = f2bf(w0[i]);
    if (i < 128 * 128) w1b[i] = f2bf(w1[i]);
}

// ---------------- Fused reduce + MFMA MLP ----------------
constexpr int NPB = 8;           // nodes per block (2 per wave)
constexpr int XCP = 256 + 8;     // xc row pitch (bf16); row stride 528B (16B-aligned)
constexpr int HSP = 128 + 8;     // hs row pitch (bf16); row stride 272B (16B-aligned)

__global__ __launch_bounds__(256, 8)
void fused_gcn(const unsigned short* __restrict__ x0b,
               const float* __restrict__ x0,
               const int* __restrict__ deg,      // = cursor (stride CSTR) after fill
               const unsigned short* __restrict__ esrc,
               const unsigned short* __restrict__ w0b,
               const float* __restrict__ b0,
               const unsigned short* __restrict__ w1b,
               const float* __restrict__ b1,
               float* __restrict__ out) {
    __shared__ unsigned short xc[16 * XCP];   // 8.4 KB
    __shared__ unsigned short hs[16 * HSP];   // 4.35 KB -> 12.8 KB total

    int t = threadIdx.x;
    int q = t >> 6;        // wave id (0..3)
    int l = t & 63;        // lane
    int n0 = blockIdx.x * NPB;
    int nA = n0 + q * 2;   // wave q owns nodes nA, nA+1
    int nB = nA + 1;

    bool hi = (l >= 32);        // lane parity half: hi serves odd edges of each pair
    int fo8 = (l & 31) * 8;     // bf16 element offset within the 256-elem row
    const float NEG_INF = __int_as_float(0xFF800000);

    // Bucket loads: lane l holds edge l's src id (only k < deg lanes ever read)
    int vA = esrc[nA * CAP + l];
    int vB = esrc[nB * CAP + l];
    int dA = min(__builtin_amdgcn_readfirstlane(deg[nA * CSTR]), CAP);
    int dB = min(__builtin_amdgcn_readfirstlane(deg[nB * CSTR]), CAP);

#define ACC8(r) { \
    float v0=bf2f(r[0]), v1=bf2f(r[1]), v2=bf2f(r[2]), v3=bf2f(r[3]); \
    float v4=bf2f(r[4]), v5=bf2f(r[5]), v6=bf2f(r[6]), v7=bf2f(r[7]); \
    S0+=v0;S1+=v1;S2+=v2;S3+=v3;S4+=v4;S5+=v5;S6+=v6;S7+=v7; \
    M0=fmaxf(M0,v0);M1=fmaxf(M1,v1);M2=fmaxf(M2,v2);M3=fmaxf(M3,v3); \
    M4=fmaxf(M4,v4);M5=fmaxf(M5,v5);M6=fmaxf(M6,v6);M7=fmaxf(M7,v7); }

// one dwordx4 wave-instruction = 2 edges: lo lanes edge k, hi lanes edge k+1
#define PAIR_LOAD(vv, k, rname) \
    int ue##rname = __builtin_amdgcn_readlane(vv, (k));     ue##rname = (ue##rname < NN) ? ue##rname : 0; \
    int uo##rname = __builtin_amdgcn_readlane(vv, (k) + 1); uo##rname = (uo##rname < NN) ? uo##rname : 0; \
    int us##rname = hi ? uo##rname : ue##rname; \
    short8 rname = *(const short8*)&x0b[(us##rname << 8) + fo8];

#define GATHER_NODE(vv, dd, nn, g) { \
    float S0=0,S1=0,S2=0,S3=0,S4=0,S5=0,S6=0,S7=0; \
    float M0=NEG_INF,M1=NEG_INF,M2=NEG_INF,M3=NEG_INF; \
    float M4=NEG_INF,M5=NEG_INF,M6=NEG_INF,M7=NEG_INF; \
    int kk = 0; \
    for (; kk + 7 < dd; kk += 8) {          /* 4 loads in flight, 8 edges */ \
        PAIR_LOAD(vv, kk,     ra) PAIR_LOAD(vv, kk + 2, rb) \
        PAIR_LOAD(vv, kk + 4, rc) PAIR_LOAD(vv, kk + 6, rd) \
        ACC8(ra) ACC8(rb) ACC8(rc) ACC8(rd) \
    } \
    if (kk + 3 < dd) { \
        PAIR_LOAD(vv, kk, ra) PAIR_LOAD(vv, kk + 2, rb) \
        ACC8(ra) ACC8(rb) \
        kk += 4; \
    } \
    if (kk + 1 < dd) { \
        PAIR_LOAD(vv, kk, ra) \
        ACC8(ra) \
        kk += 2; \
    } \
    if (dd & 1) {                            /* single tail edge: lo half only */ \
        int ut = __builtin_amdgcn_readlane(vv, dd - 1); ut = (ut < NN) ? ut : 0; \
        short8 rt = *(const short8*)&x0b[(ut << 8) + fo8]; \
        if (!hi) { ACC8(rt) } \
    } \
    /* combine even/odd halves across the 32-lane boundary */ \
    { float o; \
      o=__shfl_xor(S0,32); S0+=o; o=__shfl_xor(S1,32); S1+=o; \
      o=__shfl_xor(S2,32); S2+=o; o=__shfl_xor(S3,32); S3+=o; \
      o=__shfl_xor(S4,32); S4+=o; o=__shfl_xor(S5,32); S5+=o; \
      o=__shfl_xor(S6,32); S6+=o; o=__shfl_xor(S7,32); S7+=o; \
      o=__shfl_xor(M0,32); M0=fmaxf(M0,o); o=__shfl_xor(M1,32); M1=fmaxf(M1,o); \
      o=__shfl_xor(M2,32); M2=fmaxf(M2,o); o=__shfl_xor(M3,32); M3=fmaxf(M3,o); \
      o=__shfl_xor(M4,32); M4=fmaxf(M4,o); o=__shfl_xor(M5,32); M5=fmaxf(M5,o); \
      o=__shfl_xor(M6,32); M6=fmaxf(M6,o); o=__shfl_xor(M7,32); M7=fmaxf(M7,o); } \
    if (!hi) { \
        float e0,e1,e2,e3,e4,e5,e6,e7, a0,a1,a2,a3,a4,a5,a6,a7; \
        if (dd > 0) { \
            float inv = 1.0f / (float)dd; \
            e0=S0*inv;e1=S1*inv;e2=S2*inv;e3=S3*inv;e4=S4*inv;e5=S5*inv;e6=S6*inv;e7=S7*inv; \
            a0=M0;a1=M1;a2=M2;a3=M3;a4=M4;a5=M5;a6=M6;a7=M7; \
        } else { \
            short8 rr = *(const short8*)&x0b[((nn) << 8) + fo8]; \
            e0=a0=bf2f(rr[0]); e1=a1=bf2f(rr[1]); e2=a2=bf2f(rr[2]); e3=a3=bf2f(rr[3]); \
            e4=a4=bf2f(rr[4]); e5=a5=bf2f(rr[5]); e6=a6=bf2f(rr[6]); e7=a7=bf2f(rr[7]); \
        } \
        int row = (q * 2 + g) * 2 + (l >> 4);      /* l<32: batch = l>>4 */ \
        int fb  = (l & 15) * 8; \
        short8 mv = { (short)f2bf(e0),(short)f2bf(e1),(short)f2bf(e2),(short)f2bf(e3), \
                      (short)f2bf(e4),(short)f2bf(e5),(short)f2bf(e6),(short)f2bf(e7) }; \
        short8 av = { (short)f2bf(a0),(short)f2bf(a1),(short)f2bf(a2),(short)f2bf(a3), \
                      (short)f2bf(a4),(short)f2bf(a5),(short)f2bf(a6),(short)f2bf(a7) }; \
        *(short8*)&xc[row * XCP + fb]       = mv; \
        *(short8*)&xc[row * XCP + 128 + fb] = av; \
    } \
}

    GATHER_NODE(vA, dA, nA, 0)
    GATHER_NODE(vB, dB, nB, 1)
#undef GATHER_NODE
#undef PAIR_LOAD
#undef ACC8
    __syncthreads();

    // ---- MFMA MLP: 16 rows x 128 cols; wave q owns 32 cols (2 tiles of 16) ----
    int m    = l & 15;
    int quad = l >> 4;
    int colbase = q * 32;

    floatx4 acc[2];
#pragma unroll
    for (int ct = 0; ct < 2; ++ct) acc[ct] = (floatx4){0.f, 0.f, 0.f, 0.f};
#pragma unroll
    for (int ks = 0; ks < 8; ++ks) {
        short8 a = *(const short8*)&xc[m * XCP + ks * 32 + quad * 8];
#pragma unroll
        for (int ct = 0; ct < 2; ++ct) {
            short8 bfr = *(const short8*)&w0b[(colbase + ct * 16 + m) * 256 + ks * 32 + quad * 8];
            acc[ct] = __builtin_amdgcn_mfma_f32_16x16x32_bf16(a, bfr, acc[ct], 0, 0, 0);
        }
    }
#pragma unroll
    for (int ct = 0; ct < 2; ++ct) {
        int col = colbase + ct * 16 + m;
        float bias = b0[col];
#pragma unroll
        for (int r = 0; r < 4; ++r) {
            int row = quad * 4 + r;
            hs[row * HSP + col] = f2bf(fmaxf(acc[ct][r] + bias, 0.0f));
        }
    }
    __syncthreads();

    floatx4 acc2[2];
#pragma unroll
    for (int ct = 0; ct < 2; ++ct) acc2[ct] = (floatx4){0.f, 0.f, 0.f, 0.f};
#pragma unroll
    for (int ks = 0; ks < 4; ++ks) {
        short8 a = *(const short8*)&hs[m * HSP + ks * 32 + quad * 8];
#pragma unroll
        for (int ct = 0; ct < 2; ++ct) {
            short8 bfr = *(const short8*)&w1b[(colbase + ct * 16 + m) * 128 + ks * 32 + quad * 8];
            acc2[ct] = __builtin_amdgcn_mfma_f32_16x16x32_bf16(a, bfr, acc2[ct], 0, 0, 0);
        }
    }
#pragma unroll
    for (int ct = 0; ct < 2; ++ct) {
        int col = colbase + ct * 16 + m;
        float bias = b1[col];
#pragma unroll
        for (int r = 0; r < 4; ++r) {
            int row = quad * 4 + r;
            int n  = n0 + (row >> 1);
            int b2 = row & 1;
            int oi = (b2 * NN + n) * FF + col;
            float xv = __builtin_nontemporal_load(&x0[oi]);
            __builtin_nontemporal_store(xv + bias + acc2[ct][r], &out[oi]);
        }
    }
}

extern "C" void kernel_launch(void* const* d_in, const int* in_sizes, int n_in,
                              void* d_out, int out_size, void* d_ws, size_t ws_size,
                              hipStream_t stream) {
    const float* x0  = (const float*)d_in[0];
    const int*   dst = (const int*)d_in[1];
    const int*   src = (const int*)d_in[2];
    const float* w0  = (const float*)d_in[3];
    const float* b0  = (const float*)d_in[4];
    const float* w1  = (const float*)d_in[5];
    const float* b1  = (const float*)d_in[6];
    float* out = (float*)d_out;
    int E = in_sizes[1];

    // ws layout: cursor (NN*CSTR ints, padded) | esrc (NN*CAP ushort) | x0b | w0b | w1b
    int* cursor = (int*)d_ws;
    unsigned short* esrc = (unsigned short*)(cursor + (size_t)NN * CSTR);
    unsigned short* x0b  = esrc + (size_t)NN * CAP;
    unsigned short* w0b  = x0b + NBF2;
    unsigned short* w1b  = w0b + 128 * 256;

    int eb = (E + 255) / 256;

    hipMemsetAsync(cursor, 0, (size_t)NN * CSTR * sizeof(int), stream);
    convert_fill<<<eb, 256, 0, stream>>>(dst, src, E, x0, w0, w1, cursor, esrc, x0b, w0b, w1b);
    fused_gcn<<<NN / NPB, 256, 0, stream>>>(x0b, x0, cursor, esrc, w0b, b0, w1b, b1, out);
}